// Round 14
// baseline (232.825 us; speedup 1.0000x reference)
//
#include <hip/hip_runtime.h>
#include <hip/hip_bf16.h>
#include <stdint.h>

// ---------------------------------------------------------------------------
// EncoderLayer: x[16,1024,512] fp32; all matmuls in bf16 MFMA, fp32 accum.
// ---------------------------------------------------------------------------

using bf16 = __bf16;
typedef __attribute__((ext_vector_type(2))) __bf16 bf16x2;
typedef __attribute__((ext_vector_type(4))) __bf16 bf16x4;
typedef __attribute__((ext_vector_type(8))) __bf16 bf16x8;
typedef __attribute__((ext_vector_type(4))) float floatx4;
typedef __attribute__((ext_vector_type(16))) float f32x16;

#define AS1 __attribute__((address_space(1)))
#define AS3 __attribute__((address_space(3)))

#define L2E 1.44269504088896340736f

constexpr int BN_ = 16, SQ_ = 1024, DM_ = 512, DFF_ = 2048, NH_ = 8, DK_ = 64;
constexpr int ROWS_ = BN_ * SQ_;   // 16384

// --------------------------------------------- fp32->bf16, 5 tensors, 1 launch
__device__ __forceinline__ void f2b_one(const float* __restrict__ in,
                                        bf16* __restrict__ out, int i) {
  float4 a = ((const float4*)in)[2 * i];
  float4 b = ((const float4*)in)[2 * i + 1];
  bf16x8 o;
  o[0] = (bf16)a.x; o[1] = (bf16)a.y; o[2] = (bf16)a.z; o[3] = (bf16)a.w;
  o[4] = (bf16)b.x; o[5] = (bf16)b.y; o[6] = (bf16)b.z; o[7] = (bf16)b.w;
  ((bf16x8*)out)[i] = o;
}

__global__ __launch_bounds__(256) void f2b5_kernel(
    const float* __restrict__ s0, bf16* __restrict__ d0, int n0,
    const float* __restrict__ s1, bf16* __restrict__ d1, int n1,
    const float* __restrict__ s2, bf16* __restrict__ d2, int n2,
    const float* __restrict__ s3, bf16* __restrict__ d3, int n3,
    const float* __restrict__ s4, bf16* __restrict__ d4, int n4) {
  int i = blockIdx.x * 256 + threadIdx.x;
  if (i < n0) { f2b_one(s0, d0, i); return; }  i -= n0;
  if (i < n1) { f2b_one(s1, d1, i); return; }  i -= n1;
  if (i < n2) { f2b_one(s2, d2, i); return; }  i -= n2;
  if (i < n3) { f2b_one(s3, d3, i); return; }  i -= n3;
  if (i < n4) { f2b_one(s4, d4, i); }
}

// ------------------------------------------------------------------- GEMM BK32
// 128x128 tile, BK=32, dbuf counted vmcnt(4). [proven round-4 structure]
// Used for ffn1 (grid 2048 blocks wants 5 blocks/CU -> keep 32KB LDS).
template <int RELU>
__global__ __launch_bounds__(256) void gemm_bt(const bf16* __restrict__ A,
                                               const bf16* __restrict__ B,
                                               const float* __restrict__ bias,
                                               bf16* __restrict__ C,
                                               int M, int N, int K) {
  __shared__ char glds[32768];   // [A dbuf 2x8KB][B dbuf 2x8KB]
  const int tid = threadIdx.x;
  const int lane = tid & 63;
  const int wv = tid >> 6;
  const int wr = wv >> 1, wc = wv & 1;
  const int r15 = lane & 15, g = lane >> 4;
  const int tileN = blockIdx.x * 128;
  const int tileM = blockIdx.y * 128;

  floatx4 acc[4][4] = {};

  uint32_t dstoff[2];
  const bf16* srcA[2];
  const bf16* srcB[2];
#pragma unroll
  for (int is = 0; is < 2; ++is) {
    const int base = wv * 2048 + is * 1024;
    const int ob = base + lane * 16;
    const int row = ob >> 6;
    const int pslot = (ob >> 4) & 3;
    const int sslot = pslot ^ ((row >> 1) & 3);
    dstoff[is] = base;
    srcA[is] = A + (size_t)(tileM + row) * K + sslot * 8;
    srcB[is] = B + (size_t)(tileN + row) * K + sslot * 8;
  }

#define GSTAGE(buf, kt)                                                         \
  {                                                                             \
    _Pragma("unroll")                                                           \
    for (int is = 0; is < 2; ++is) {                                            \
      __builtin_amdgcn_global_load_lds(                                         \
          (AS1 uint32_t*)(srcA[is] + (kt) * 32),                                \
          (AS3 uint32_t*)((AS3 char*)glds + (buf) * 8192 + dstoff[is]), 16, 0, 0); \
      __builtin_amdgcn_global_load_lds(                                         \
          (AS1 uint32_t*)(srcB[is] + (kt) * 32),                                \
          (AS3 uint32_t*)((AS3 char*)glds + 16384 + (buf) * 8192 + dstoff[is]), \
          16, 0, 0);                                                            \
    }                                                                           \
  }

  uint32_t aoff[4], boff[4];
#pragma unroll
  for (int m = 0; m < 4; ++m) {
    const int arow = wr * 64 + m * 16 + r15;
    aoff[m] = (uint32_t)((arow * 64 + g * 16) ^ (((arow >> 1) & 3) << 4));
  }
#pragma unroll
  for (int n = 0; n < 4; ++n) {
    const int brow = wc * 64 + n * 16 + r15;
    boff[n] = (uint32_t)((brow * 64 + g * 16) ^ (((brow >> 1) & 3) << 4));
  }

  const int nk = K >> 5;
  GSTAGE(0, 0);

  for (int kt = 0; kt < nk; ++kt) {
    const int cur = kt & 1;
    if (kt + 1 < nk) {
      GSTAGE(cur ^ 1, kt + 1);
      asm volatile("s_waitcnt vmcnt(4)" ::: "memory");
    } else {
      asm volatile("s_waitcnt vmcnt(0)" ::: "memory");
    }
    __builtin_amdgcn_s_barrier();
    __builtin_amdgcn_sched_barrier(0);

    const char* Ac = (const char*)glds + cur * 8192;
    const char* Bc = (const char*)glds + 16384 + cur * 8192;

    bf16x8 af[4], bfr[4];
#pragma unroll
    for (int m = 0; m < 4; ++m) af[m] = *(const bf16x8*)(Ac + aoff[m]);
#pragma unroll
    for (int n = 0; n < 4; ++n) bfr[n] = *(const bf16x8*)(Bc + boff[n]);
#pragma unroll
    for (int m = 0; m < 4; ++m)
#pragma unroll
      for (int n = 0; n < 4; ++n)
        acc[m][n] = __builtin_amdgcn_mfma_f32_16x16x32_bf16(af[m], bfr[n],
                                                            acc[m][n], 0, 0, 0);
    __builtin_amdgcn_s_barrier();
  }
#undef GSTAGE

#pragma unroll
  for (int n = 0; n < 4; ++n) {
    const int col = tileN + wc * 64 + n * 16 + r15;
    const float bv = bias[col];
#pragma unroll
    for (int m = 0; m < 4; ++m) {
      const int row0 = tileM + wr * 64 + m * 16 + g * 4;
#pragma unroll
      for (int j = 0; j < 4; ++j) {
        float v = acc[m][n][j] + bv;
        if (RELU) v = fmaxf(v, 0.f);
        C[(size_t)(row0 + j) * N + col] = (bf16)v;
      }
    }
  }
}

// ------------------------------------------------------------------- GEMM BK64
// 128x128 tile, BK=64. [r10 win: for the 512-block GEMMs capped at 2 blk/CU]
template <int RELU>
__global__ __launch_bounds__(256) void gemm_bt64(const bf16* __restrict__ A,
                                                 const bf16* __restrict__ B,
                                                 const float* __restrict__ bias,
                                                 bf16* __restrict__ C,
                                                 int M, int N, int K) {
  __shared__ char glds[65536];   // [A dbuf 2x16KB][B dbuf 2x16KB]
  const int tid = threadIdx.x;
  const int lane = tid & 63;
  const int wv = tid >> 6;
  const int wr = wv >> 1, wc = wv & 1;
  const int r15 = lane & 15, g = lane >> 4;
  const int tileN = blockIdx.x * 128;
  const int tileM = blockIdx.y * 128;

  floatx4 acc[4][4] = {};

  uint32_t dstoff[4];
  const bf16* srcA[4];
  const bf16* srcB[4];
#pragma unroll
  for (int is = 0; is < 4; ++is) {
    const int base = is * 4096 + wv * 1024;
    const int ob = base + lane * 16;
    const int row = ob >> 7;                  // 128B per row
    const int pslot = (ob >> 4) & 7;
    const int sslot = pslot ^ (row & 7);      // inverse-swizzled source slot
    dstoff[is] = base;
    srcA[is] = A + (size_t)(tileM + row) * K + sslot * 8;
    srcB[is] = B + (size_t)(tileN + row) * K + sslot * 8;
  }

#define GSTAGE64(buf, kt)                                                        \
  {                                                                              \
    _Pragma("unroll")                                                            \
    for (int is = 0; is < 4; ++is) {                                             \
      __builtin_amdgcn_global_load_lds(                                          \
          (AS1 uint32_t*)(srcA[is] + (kt) * 64),                                 \
          (AS3 uint32_t*)((AS3 char*)glds + (buf) * 16384 + dstoff[is]), 16, 0, 0); \
      __builtin_amdgcn_global_load_lds(                                          \
          (AS1 uint32_t*)(srcB[is] + (kt) * 64),                                 \
          (AS3 uint32_t*)((AS3 char*)glds + 32768 + (buf) * 16384 + dstoff[is]), \
          16, 0, 0);                                                             \
    }                                                                            \
  }

  uint32_t abase[4], ax[4], bbase[4], bx[4];
#pragma unroll
  for (int m = 0; m < 4; ++m) {
    const int arow = wr * 64 + m * 16 + r15;
    abase[m] = (uint32_t)(arow * 128);
    ax[m] = (uint32_t)(arow & 7);
  }
#pragma unroll
  for (int n = 0; n < 4; ++n) {
    const int brow = wc * 64 + n * 16 + r15;
    bbase[n] = (uint32_t)(brow * 128);
    bx[n] = (uint32_t)(brow & 7);
  }

  const int nk = K >> 6;
  GSTAGE64(0, 0);

  for (int kt = 0; kt < nk; ++kt) {
    const int cur = kt & 1;
    if (kt + 1 < nk) {
      GSTAGE64(cur ^ 1, kt + 1);
      asm volatile("s_waitcnt vmcnt(8)" ::: "memory");
    } else {
      asm volatile("s_waitcnt vmcnt(0)" ::: "memory");
    }
    __builtin_amdgcn_s_barrier();
    __builtin_amdgcn_sched_barrier(0);

    const char* Ac = (const char*)glds + cur * 16384;
    const char* Bc = (const char*)glds + 32768 + cur * 16384;

#pragma unroll
    for (int kk = 0; kk < 2; ++kk) {
      bf16x8 af[4], bfr[4];
#pragma unroll
      for (int m = 0; m < 4; ++m) {
        const uint32_t slot = (uint32_t)(kk * 4 + g) ^ ax[m];
        af[m] = *(const bf16x8*)(Ac + abase[m] + slot * 16);
      }
#pragma unroll
      for (int n = 0; n < 4; ++n) {
        const uint32_t slot = (uint32_t)(kk * 4 + g) ^ bx[n];
        bfr[n] = *(const bf16x8*)(Bc + bbase[n] + slot * 16);
      }
#pragma unroll
      for (int m = 0; m < 4; ++m)
#pragma unroll
        for (int n = 0; n < 4; ++n)
          acc[m][n] = __builtin_amdgcn_mfma_f32_16x16x32_bf16(af[m], bfr[n],
                                                              acc[m][n], 0, 0, 0);
    }
    __builtin_amdgcn_s_barrier();
  }
#undef GSTAGE64

#pragma unroll
  for (int n = 0; n < 4; ++n) {
    const int col = tileN + wc * 64 + n * 16 + r15;
    const float bv = bias[col];
#pragma unroll
    for (int m = 0; m < 4; ++m) {
      const int row0 = tileM + wr * 64 + m * 16 + g * 4;
#pragma unroll
      for (int j = 0; j < 4; ++j) {
        float v = acc[m][n][j] + bv;
        if (RELU) v = fmaxf(v, 0.f);
        C[(size_t)(row0 + j) * N + col] = (bf16)v;
      }
    }
  }
}

// ----------------------------------------------------------- flash attention
// Split-K over KV (r12), fixed-shift softmax m==0 (r13). THIS ROUND:
//  - issue-early tr_reads: all 16 ds_read_b64_tr_b16 issued BEFORE the P-pack
//    (pack VALU hides LDS latency; one lgkmcnt wait per pass instead of two;
//    single 16-MFMA PV cluster).
//  - deferred cross-half l-sum: per-pass shfl removed; one shfl after the loop
//    (exact: with m==0 lstate is a plain sum).
__global__ __launch_bounds__(512) void attn_kernel(const bf16* __restrict__ qkv,
                                                   bf16* __restrict__ ctx) {
  __shared__ char lds[34816];   // 4 x 8KB dbuf (2 groups x 2 bufs) + 2KB m/l

  const int tid = threadIdx.x;
  const int lane = tid & 63;
  const int wv = tid >> 6;        // 0..7
  const int wq = wv & 3;          // q-subtile index
  const int grp = wv >> 2;        // KV half: 0 -> rows 0..511, 1 -> 512..1023
  const int l31 = lane & 31;
  const int h = lane >> 5;
  const int b = blockIdx.z, hd = blockIdx.y, qt = blockIdx.x;
  const size_t headoff = (size_t)b * SQ_ * DM_ + hd * DK_;
  const int q0 = qt * 128 + wq * 32;
  const int go = grp * 512;       // KV row offset for this group

  const float QS = 0.125f * L2E;
  bf16x8 aq[4];
#pragma unroll
  for (int kd = 0; kd < 4; ++kd) {
    const bf16* gq = qkv + headoff + (size_t)(q0 + l31) * DM_ + kd * 16 + h * 8;
    bf16x8 v = *(const bf16x8*)gq;
#pragma unroll
    for (int e = 0; e < 8; ++e) v[e] = (bf16)((float)v[e] * QS);
    aq[kd] = v;
  }

  f32x16 o0 = {}, o1 = {};
  float lstate = 0.f;

  const uint32_t ldsb = (uint32_t)(uintptr_t)(AS3 char*)lds;

  // ---- staging precompute (64-row subtiled tile, proven r9 formula)
  uint32_t dstoff[2];
  const bf16* srcb[2];
#pragma unroll
  for (int is = 0; is < 2; ++is) {
    const int ob = is * 4096 + wq * 1024 + lane * 16;
    const int e0 = ob >> 1;
    const int srow = ((e0 >> 8) << 2) + ((e0 >> 4) & 3);
    const int dcol = ((e0 >> 6) & 3) * 16 + ((e0 >> 3) & 1) * 8;
    dstoff[is] = (uint32_t)(grp * 16384 + is * 4096 + wq * 1024);
    srcb[is] = qkv + headoff + (size_t)(go + srow) * DM_ + dcol;
  }

#define STAGE(buf, t)                                                          \
  {                                                                            \
    _Pragma("unroll")                                                          \
    for (int is = 0; is < 2; ++is) {                                           \
      __builtin_amdgcn_global_load_lds(                                        \
          (AS1 uint32_t*)(srcb[is] + (size_t)(t) * 64 * DM_),                  \
          (AS3 uint32_t*)((AS3 char*)lds + (buf) * 8192 + dstoff[is]), 16, 0, 0); \
    }                                                                          \
  }

  constexpr int NT = 512 / 64;   // 8 passes per group
  STAGE(0, 0);

  for (int t = 0; t < NT; ++t) {
    const int cur = t & 1;
    // barrier #1: all waves done reading buf[cur^1] -> safe to overwrite
    __builtin_amdgcn_s_barrier();
    if (t + 1 < NT) {
      STAGE(cur ^ 1, t + 1);
      asm volatile("s_waitcnt vmcnt(2)" ::: "memory");   // my tile t's 2 loads
    } else {
      asm volatile("s_waitcnt vmcnt(0)" ::: "memory");
    }
    // barrier #2: all waves' stage of buf[cur] visible
    __builtin_amdgcn_s_barrier();
    __builtin_amdgcn_sched_barrier(0);

    const char* tile = (const char*)lds + grp * 16384 + cur * 8192;

    // ---- S^T = K · Q^T (log2 domain)
    f32x16 s0v = {}, s1v = {};
    const char* pabase = tile + (l31 >> 2) * 512 + (l31 & 3) * 32 + h * 16;
    __builtin_amdgcn_s_setprio(1);
#pragma unroll
    for (int kd = 0; kd < 4; ++kd) {
      bf16x8 a0 = *(const bf16x8*)(pabase + kd * 128);
      bf16x8 a1 = *(const bf16x8*)(pabase + kd * 128 + 4096);
      s0v = __builtin_amdgcn_mfma_f32_32x32x16_bf16(a0, aq[kd], s0v, 0, 0, 0);
      s1v = __builtin_amdgcn_mfma_f32_32x32x16_bf16(a1, aq[kd], s1v, 0, 0, 0);
    }
    __builtin_amdgcn_s_setprio(0);

    // ---- fixed-shift softmax accumulation: P = exp2(S), no max tracking
    // (cross-half sum deferred to after the KV loop)
    float rs = 0.f;
#pragma unroll
    for (int r = 0; r < 16; ++r) {
      float pq = exp2f(s0v[r]);
      s0v[r] = pq; rs += pq;
    }
#pragma unroll
    for (int r = 0; r < 16; ++r) {
      float pq = exp2f(s1v[r]);
      s1v[r] = pq; rs += pq;
    }
    lstate += rs;

    // ---- issue ALL tr_reads early (T14): pack VALU below hides LDS latency
    bf16x4 lo[2][4], hi[2][4];
#pragma unroll
    for (int df = 0; df < 2; ++df) {
      const uint32_t vb = ldsb + grp * 16384 + cur * 8192 + df * 256 +
                          (lane & 15) * 8 + ((lane >> 4) & 1) * 128 +
                          (lane >> 5) * 1024;
#pragma unroll
      for (int ks = 0; ks < 4; ++ks) {
        asm volatile("ds_read_b64_tr_b16 %0, %2\n\t"
                     "ds_read_b64_tr_b16 %1, %2 offset:512"
                     : "=&v"(lo[df][ks]), "=&v"(hi[df][ks])
                     : "v"(vb + ks * 2048));
      }
    }

    // ---- build PV B-fragments: bf16 pairs + permlane32_swap (proven)
    uint32_t pf[4][4];
#pragma unroll
    for (int ks = 0; ks < 4; ++ks) {
      const int kb = (ks & 1) * 8;
      float v0, v1, v2, v3, v4, v5, v6, v7;
      if (ks < 2) {
        v0 = s0v[kb+0]; v1 = s0v[kb+1]; v2 = s0v[kb+2]; v3 = s0v[kb+3];
        v4 = s0v[kb+4]; v5 = s0v[kb+5]; v6 = s0v[kb+6]; v7 = s0v[kb+7];
      } else {
        v0 = s1v[kb+0]; v1 = s1v[kb+1]; v2 = s1v[kb+2]; v3 = s1v[kb+3];
        v4 = s1v[kb+4]; v5 = s1v[kb+5]; v6 = s1v[kb+6]; v7 = s1v[kb+7];
      }
      union { bf16x2 v; uint32_t u; } P0, P1, P2, P3;
      P0.v = bf16x2{(bf16)v0, (bf16)v1};
      P1.v = bf16x2{(bf16)v2, (bf16)v3};
      P2.v = bf16x2{(bf16)v4, (bf16)v5};
      P3.v = bf16x2{(bf16)v6, (bf16)v7};
      asm volatile("v_permlane32_swap_b32 %0, %1" : "+v"(P0.u), "+v"(P2.u));
      asm volatile("v_permlane32_swap_b32 %0, %1" : "+v"(P1.u), "+v"(P3.u));
      pf[ks][0] = P0.u;
      pf[ks][1] = P1.u;
      pf[ks][2] = P2.u;
      pf[ks][3] = P3.u;
    }

    // ---- PV: one wait, 16-MFMA cluster
    asm volatile("s_waitcnt lgkmcnt(0)" ::: "memory");
    __builtin_amdgcn_sched_barrier(0);
    __builtin_amdgcn_s_setprio(1);
#pragma unroll
    for (int df = 0; df < 2; ++df)
#pragma unroll
      for (int ks = 0; ks < 4; ++ks) {
        union { struct { bf16x4 l, h; } pp; bf16x8 v; } av;
        av.pp.l = lo[df][ks]; av.pp.h = hi[df][ks];
        union { uint32_t u[4]; bf16x8 v; } bv;
        bv.u[0] = pf[ks][0]; bv.u[1] = pf[ks][1];
        bv.u[2] = pf[ks][2]; bv.u[3] = pf[ks][3];
        if (df == 0)
          o0 = __builtin_amdgcn_mfma_f32_32x32x16_bf16(av.v, bv.v, o0, 0, 0, 0);
        else
          o1 = __builtin_amdgcn_mfma_f32_32x32x16_bf16(av.v, bv.v, o1, 0, 0, 0);
      }
    __builtin_amdgcn_s_setprio(0);
  }
#undef STAGE

  // ---- deferred cross-half l-sum (exact: plain sum with m==0)
  lstate += __shfl_xor(lstate, 32);

  // ---- flash combine (m==0 both groups: plain sums, no exp factors)
  __syncthreads();   // all staging reads done -> LDS reusable
  if (grp == 1) {
    float* dst = (float*)((char*)lds + wq * 8192) + lane * 32;
#pragma unroll
    for (int r = 0; r < 16; ++r) { dst[r] = o0[r]; dst[16 + r] = o1[r]; }
    float* ml = (float*)((char*)lds + 32768 + wq * 512 + lane * 8);
    *ml = lstate;
  }
  __syncthreads();
  if (grp == 0) {
    const float* src = (const float*)((char*)lds + wq * 8192) + lane * 32;
    const float lB = *(const float*)((const char*)lds + 32768 + wq * 512 + lane * 8);
    lstate += lB;
#pragma unroll
    for (int r = 0; r < 16; ++r) {
      o0[r] += src[r];
      o1[r] += src[16 + r];
    }
  }
  __syncthreads();   // merge reads done -> LDS reusable for transpose

  // ---- epilogue (group A only): normalize, per-wave transpose, store
  if (grp == 0) {
    const float invl = 1.f / lstate;
    char* wb = (char*)lds + wq * 4096;   // [q=32][d=64] bf16, XOR-swizzled
#pragma unroll
    for (int df = 0; df < 2; ++df)
#pragma unroll
      for (int t = 0; t < 4; ++t) {
        const f32x16& ov = df ? o1 : o0;
        bf16x4 pkt;
        pkt[0] = (bf16)(ov[4*t+0] * invl);
        pkt[1] = (bf16)(ov[4*t+1] * invl);
        pkt[2] = (bf16)(ov[4*t+2] * invl);
        pkt[3] = (bf16)(ov[4*t+3] * invl);
        const int byte = (l31 * 128 + df * 64 + t * 16 + h * 8) ^ ((l31 & 7) << 4);
        *(bf16x4*)(wb + byte) = pkt;
      }
#pragma unroll
    for (int ps = 0; ps < 4; ++ps) {
      const int qr = ps * 8 + (lane >> 3);
      const int byte = (qr * 128 + (lane & 7) * 16) ^ ((qr & 7) << 4);
      bf16x8 vv = *(const bf16x8*)(wb + byte);
      bf16* dst = ctx + (size_t)(b * SQ_ + q0 + qr) * DM_ + hd * 64 + (lane & 7) * 8;
      *(bf16x8*)dst = vv;
    }
  }
}

// ------------------------------------------------- dual LayerNorm residual #1
__global__ __launch_bounds__(256) void dual_ln_kernel(const bf16* __restrict__ x,
                                                      const bf16* __restrict__ attn,
                                                      const float* __restrict__ g1,
                                                      const float* __restrict__ be1,
                                                      bf16* __restrict__ out) {
  const int row = blockIdx.x * 4 + (threadIdx.x >> 6);
  const int lane = threadIdx.x & 63;
  bf16x8 xv = *(const bf16x8*)(x + (size_t)row * DM_ + lane * 8);
  bf16x8 av = *(const bf16x8*)(attn + (size_t)row * DM_ + lane * 8);
  float xs[8], as_[8];
#pragma unroll
  for (int e = 0; e < 8; ++e) { xs[e] = (float)xv[e]; as_[e] = (float)av[e]; }
  float sx = 0, sx2 = 0, sa = 0, sa2 = 0;
#pragma unroll
  for (int e = 0; e < 8; ++e) {
    sx += xs[e]; sx2 += xs[e] * xs[e];
    sa += as_[e]; sa2 += as_[e] * as_[e];
  }
#pragma unroll
  for (int off = 1; off < 64; off <<= 1) {
    sx += __shfl_xor(sx, off);  sx2 += __shfl_xor(sx2, off);
    sa += __shfl_xor(sa, off);  sa2 += __shfl_xor(sa2, off);
  }
  const float inv = 1.f / (float)DM_;
  const float mux = sx * inv, mua = sa * inv;
  const float rx = rsqrtf(fmaxf(sx2 * inv - mux * mux, 0.f) + 1e-5f);
  const float ra = rsqrtf(fmaxf(sa2 * inv - mua * mua, 0.f) + 1e-5f);
  bf16x8 ov;
#pragma unroll
  for (int e = 0; e < 8; ++e) {
    const int c = lane * 8 + e;
    const float val = ((xs[e] - mux) * rx + (as_[e] - mua) * ra) * g1[c] + 2.f * be1[c];
    ov[e] = (bf16)val;
  }
  *(bf16x8*)(out + (size_t)row * DM_ + lane * 8) = ov;
}

// ------------------------------------------------------ final LN residual #2
__global__ __launch_bounds__(256) void final_ln_kernel(const bf16* __restrict__ x1,
                                                       const bf16* __restrict__ ffn,
                                                       const float* __restrict__ g2,
                                                       const float* __restrict__ be2,
                                                       float* __restrict__ out) {
  const int row = blockIdx.x * 4 + (threadIdx.x >> 6);
  const int lane = threadIdx.x & 63;
  bf16x8 xv = *(const bf16x8*)(x1 + (size_t)row * DM_ + lane * 8);
  bf16x8 fv = *(const bf16x8*)(ffn + (size_t)row * DM_ + lane * 8);
  float fs[8];
#pragma unroll
  for (int e = 0; e < 8; ++e) fs[e] = (float)fv[e];
  float sf = 0, sf2 = 0;
#pragma unroll
  for (int e = 0; e < 8; ++e) { sf += fs[e]; sf2 += fs[e] * fs[e]; }
#pragma unroll
  for (int off = 1; off < 64; off <<= 1) {
    sf += __shfl_xor(sf, off);  sf2 += __shfl_xor(sf2, off);
  }
  const float inv = 1.f / (float)DM_;
  const float mu = sf * inv;
  const float rs = rsqrtf(fmaxf(sf2 * inv - mu * mu, 0.f) + 1e-5f);
  float ov[8];
#pragma unroll
  for (int e = 0; e < 8; ++e) {
    const int c = lane * 8 + e;
    ov[e] = (float)xv[e] + (fs[e] - mu) * rs * g2[c] + be2[c];
  }
  float* orow = out + (size_t)row * DM_ + lane * 8;
  float4 o0 = {ov[0], ov[1], ov[2], ov[3]};
  float4 o1 = {ov[4], ov[5], ov[6], ov[7]};
  ((float4*)orow)[0] = o0;
  ((float4*)orow)[1] = o1;
}

// ---------------------------------------------------------------------------
extern "C" void kernel_launch(void* const* d_in, const int* in_sizes, int n_in,
                              void* d_out, int out_size, void* d_ws, size_t ws_size,
                              hipStream_t stream) {
  const float* x     = (const float*)d_in[0];
  const float* w_qkv = (const float*)d_in[1];
  const float* b_qkv = (const float*)d_in[2];
  const float* w_out = (const float*)d_in[3];
  const float* b_out = (const float*)d_in[4];
  const float* w1    = (const float*)d_in[5];
  const float* b1    = (const float*)d_in[6];
  const float* w2    = (const float*)d_in[7];
  const float* b2    = (const float*)d_in[8];
  const float* g1    = (const float*)d_in[9];
  const float* be1   = (const float*)d_in[10];
  const float* g2    = (const float*)d_in[11];
  const float* be2   = (const float*)d_in[12];
  float* out = (float*)d_out;

  char* ws = (char*)d_ws;
  const size_t o_wqkv = 0;
  const size_t o_wout = o_wqkv + (size_t)DM_ * DM_ * 2;
  const size_t o_w1   = o_wout + (size_t)DM_ * DM_ * 2;
  const size_t o_w2   = o_w1 + (size_t)DFF_ * DM_ * 2;
  const size_t o_A    = o_w2 + (size_t)DM_ * DFF_ * 2;     // ctx_bf
  const size_t o_B    = o_A + (size_t)ROWS_ * DM_ * 2;     // qkv_bf -> x1_bf
  const size_t o_C    = o_B + (size_t)ROWS_ * DM_ * 2;     // attn_bf -> ffn_bf
  const size_t o_D    = o_C + (size_t)ROWS_ * DM_ * 2;     // x_bf -> h1_bf [ROWS,DFF]
  const size_t need   = o_D + (size_t)ROWS_ * DFF_ * 2;
  if (ws_size < need) return;

  bf16* wqkv_bf = (bf16*)(ws + o_wqkv);
  bf16* wout_bf = (bf16*)(ws + o_wout);
  bf16* w1_bf   = (bf16*)(ws + o_w1);
  bf16* w2_bf   = (bf16*)(ws + o_w2);
  bf16* bufA    = (bf16*)(ws + o_A);
  bf16* bufB    = (bf16*)(ws + o_B);
  bf16* bufC    = (bf16*)(ws + o_C);
  bf16* bufD    = (bf16*)(ws + o_D);   // x_bf lives here until ffn1 overwrites

  // 1. converts — single launch (x_bf parked in bufD; reused by GEMM1 + dual_ln)
  const int nx  = ROWS_ * DM_ / 8;       // 1048576
  const int nwq = DM_ * DM_ / 8;         // 32768
  const int nw1 = DFF_ * DM_ / 8;        // 131072
  const int ntot = nx + 2 * nwq + 2 * nw1;
  f2b5_kernel<<<dim3((ntot + 255) / 256), dim3(256), 0, stream>>>(
      x, bufD, nx,
      w_qkv, wqkv_bf, nwq,
      w_out, wout_bf, nwq,
      w1, w1_bf, nw1,
      w2, w2_bf, nw1);

  // 2. qkv = x @ w_qkv.T + b_qkv       [16384,512]  (BK=64)
  gemm_bt64<0><<<dim3(DM_ / 128, ROWS_ / 128), dim3(256), 0, stream>>>(bufD, wqkv_bf, b_qkv, bufB, ROWS_, DM_, DM_);

  // 3. self-attention (Q=K=V=qkv) -> ctx   (split-K, issue-early tr_reads)
  attn_kernel<<<dim3(SQ_ / 128, NH_, BN_), dim3(512), 0, stream>>>(bufB, bufA);

  // 4. attn = ctx @ w_out.T + b_out    (BK=64)
  gemm_bt64<0><<<dim3(DM_ / 128, ROWS_ / 128), dim3(256), 0, stream>>>(bufA, wout_bf, b_out, bufC, ROWS_, DM_, DM_);

  // 5. x1 = LN(x) + LN(attn)   (x read as bf16 from bufD)
  dual_ln_kernel<<<dim3(ROWS_ / 4), dim3(256), 0, stream>>>(bufD, bufC, g1, be1, bufB);

  // 6. h1 = relu(x1 @ w1.T + b1)       [16384,2048]  (BK=32: keep 5 blocks/CU)
  gemm_bt<1><<<dim3(DFF_ / 128, ROWS_ / 128), dim3(256), 0, stream>>>(bufB, w1_bf, b1, bufD, ROWS_, DFF_, DM_);

  // 7. ffn = h1 @ w2.T + b2            [16384,512]  (BK=64)
  gemm_bt64<0><<<dim3(DM_ / 128, ROWS_ / 128), dim3(256), 0, stream>>>(bufD, w2_bf, b2, bufC, ROWS_, DM_, DFF_);

  // 8. out = x1 + LN(ffn)
  final_ln_kernel<<<dim3(ROWS_ / 4), dim3(256), 0, stream>>>(bufB, bufC, g2, be2, out);
}

// Round 15
// 219.545 us; speedup vs baseline: 1.0605x; 1.0605x over previous
//
#include <hip/hip_runtime.h>
#include <hip/hip_bf16.h>
#include <stdint.h>

// ---------------------------------------------------------------------------
// EncoderLayer: x[16,1024,512] fp32; all matmuls in bf16 MFMA, fp32 accum.
// ---------------------------------------------------------------------------

using bf16 = __bf16;
typedef __attribute__((ext_vector_type(2))) __bf16 bf16x2;
typedef __attribute__((ext_vector_type(4))) __bf16 bf16x4;
typedef __attribute__((ext_vector_type(8))) __bf16 bf16x8;
typedef __attribute__((ext_vector_type(4))) float floatx4;
typedef __attribute__((ext_vector_type(16))) float f32x16;

#define AS1 __attribute__((address_space(1)))
#define AS3 __attribute__((address_space(3)))

#define L2E 1.44269504088896340736f

constexpr int BN_ = 16, SQ_ = 1024, DM_ = 512, DFF_ = 2048, NH_ = 8, DK_ = 64;
constexpr int ROWS_ = BN_ * SQ_;   // 16384

// --------------------------------------------- fp32->bf16, 5 tensors, 1 launch
__device__ __forceinline__ void f2b_one(const float* __restrict__ in,
                                        bf16* __restrict__ out, int i) {
  float4 a = ((const float4*)in)[2 * i];
  float4 b = ((const float4*)in)[2 * i + 1];
  bf16x8 o;
  o[0] = (bf16)a.x; o[1] = (bf16)a.y; o[2] = (bf16)a.z; o[3] = (bf16)a.w;
  o[4] = (bf16)b.x; o[5] = (bf16)b.y; o[6] = (bf16)b.z; o[7] = (bf16)b.w;
  ((bf16x8*)out)[i] = o;
}

__global__ __launch_bounds__(256) void f2b5_kernel(
    const float* __restrict__ s0, bf16* __restrict__ d0, int n0,
    const float* __restrict__ s1, bf16* __restrict__ d1, int n1,
    const float* __restrict__ s2, bf16* __restrict__ d2, int n2,
    const float* __restrict__ s3, bf16* __restrict__ d3, int n3,
    const float* __restrict__ s4, bf16* __restrict__ d4, int n4) {
  int i = blockIdx.x * 256 + threadIdx.x;
  if (i < n0) { f2b_one(s0, d0, i); return; }  i -= n0;
  if (i < n1) { f2b_one(s1, d1, i); return; }  i -= n1;
  if (i < n2) { f2b_one(s2, d2, i); return; }  i -= n2;
  if (i < n3) { f2b_one(s3, d3, i); return; }  i -= n3;
  if (i < n4) { f2b_one(s4, d4, i); }
}

// ------------------------------------------------------------------- GEMM BK32
// 128x128 tile, BK=32, dbuf counted vmcnt(4). [proven round-4 structure]
// Used for ffn1 (grid 2048 blocks wants 5 blocks/CU -> keep 32KB LDS).
template <int RELU>
__global__ __launch_bounds__(256) void gemm_bt(const bf16* __restrict__ A,
                                               const bf16* __restrict__ B,
                                               const float* __restrict__ bias,
                                               bf16* __restrict__ C,
                                               int M, int N, int K) {
  __shared__ char glds[32768];   // [A dbuf 2x8KB][B dbuf 2x8KB]
  const int tid = threadIdx.x;
  const int lane = tid & 63;
  const int wv = tid >> 6;
  const int wr = wv >> 1, wc = wv & 1;
  const int r15 = lane & 15, g = lane >> 4;
  const int tileN = blockIdx.x * 128;
  const int tileM = blockIdx.y * 128;

  floatx4 acc[4][4] = {};

  uint32_t dstoff[2];
  const bf16* srcA[2];
  const bf16* srcB[2];
#pragma unroll
  for (int is = 0; is < 2; ++is) {
    const int base = wv * 2048 + is * 1024;
    const int ob = base + lane * 16;
    const int row = ob >> 6;
    const int pslot = (ob >> 4) & 3;
    const int sslot = pslot ^ ((row >> 1) & 3);
    dstoff[is] = base;
    srcA[is] = A + (size_t)(tileM + row) * K + sslot * 8;
    srcB[is] = B + (size_t)(tileN + row) * K + sslot * 8;
  }

#define GSTAGE(buf, kt)                                                         \
  {                                                                             \
    _Pragma("unroll")                                                           \
    for (int is = 0; is < 2; ++is) {                                            \
      __builtin_amdgcn_global_load_lds(                                         \
          (AS1 uint32_t*)(srcA[is] + (kt) * 32),                                \
          (AS3 uint32_t*)((AS3 char*)glds + (buf) * 8192 + dstoff[is]), 16, 0, 0); \
      __builtin_amdgcn_global_load_lds(                                         \
          (AS1 uint32_t*)(srcB[is] + (kt) * 32),                                \
          (AS3 uint32_t*)((AS3 char*)glds + 16384 + (buf) * 8192 + dstoff[is]), \
          16, 0, 0);                                                            \
    }                                                                           \
  }

  uint32_t aoff[4], boff[4];
#pragma unroll
  for (int m = 0; m < 4; ++m) {
    const int arow = wr * 64 + m * 16 + r15;
    aoff[m] = (uint32_t)((arow * 64 + g * 16) ^ (((arow >> 1) & 3) << 4));
  }
#pragma unroll
  for (int n = 0; n < 4; ++n) {
    const int brow = wc * 64 + n * 16 + r15;
    boff[n] = (uint32_t)((brow * 64 + g * 16) ^ (((brow >> 1) & 3) << 4));
  }

  const int nk = K >> 5;
  GSTAGE(0, 0);

  for (int kt = 0; kt < nk; ++kt) {
    const int cur = kt & 1;
    if (kt + 1 < nk) {
      GSTAGE(cur ^ 1, kt + 1);
      asm volatile("s_waitcnt vmcnt(4)" ::: "memory");
    } else {
      asm volatile("s_waitcnt vmcnt(0)" ::: "memory");
    }
    __builtin_amdgcn_s_barrier();
    __builtin_amdgcn_sched_barrier(0);

    const char* Ac = (const char*)glds + cur * 8192;
    const char* Bc = (const char*)glds + 16384 + cur * 8192;

    bf16x8 af[4], bfr[4];
#pragma unroll
    for (int m = 0; m < 4; ++m) af[m] = *(const bf16x8*)(Ac + aoff[m]);
#pragma unroll
    for (int n = 0; n < 4; ++n) bfr[n] = *(const bf16x8*)(Bc + boff[n]);
#pragma unroll
    for (int m = 0; m < 4; ++m)
#pragma unroll
      for (int n = 0; n < 4; ++n)
        acc[m][n] = __builtin_amdgcn_mfma_f32_16x16x32_bf16(af[m], bfr[n],
                                                            acc[m][n], 0, 0, 0);
    __builtin_amdgcn_s_barrier();
  }
#undef GSTAGE

#pragma unroll
  for (int n = 0; n < 4; ++n) {
    const int col = tileN + wc * 64 + n * 16 + r15;
    const float bv = bias[col];
#pragma unroll
    for (int m = 0; m < 4; ++m) {
      const int row0 = tileM + wr * 64 + m * 16 + g * 4;
#pragma unroll
      for (int j = 0; j < 4; ++j) {
        float v = acc[m][n][j] + bv;
        if (RELU) v = fmaxf(v, 0.f);
        C[(size_t)(row0 + j) * N + col] = (bf16)v;
      }
    }
  }
}

// ------------------------------------------------------------------- GEMM BK64
// 128x128 tile, BK=64. [r10 win: for the 512-block GEMMs capped at 2 blk/CU]
template <int RELU>
__global__ __launch_bounds__(256) void gemm_bt64(const bf16* __restrict__ A,
                                                 const bf16* __restrict__ B,
                                                 const float* __restrict__ bias,
                                                 bf16* __restrict__ C,
                                                 int M, int N, int K) {
  __shared__ char glds[65536];   // [A dbuf 2x16KB][B dbuf 2x16KB]
  const int tid = threadIdx.x;
  const int lane = tid & 63;
  const int wv = tid >> 6;
  const int wr = wv >> 1, wc = wv & 1;
  const int r15 = lane & 15, g = lane >> 4;
  const int tileN = blockIdx.x * 128;
  const int tileM = blockIdx.y * 128;

  floatx4 acc[4][4] = {};

  uint32_t dstoff[4];
  const bf16* srcA[4];
  const bf16* srcB[4];
#pragma unroll
  for (int is = 0; is < 4; ++is) {
    const int base = is * 4096 + wv * 1024;
    const int ob = base + lane * 16;
    const int row = ob >> 7;                  // 128B per row
    const int pslot = (ob >> 4) & 7;
    const int sslot = pslot ^ (row & 7);      // inverse-swizzled source slot
    dstoff[is] = base;
    srcA[is] = A + (size_t)(tileM + row) * K + sslot * 8;
    srcB[is] = B + (size_t)(tileN + row) * K + sslot * 8;
  }

#define GSTAGE64(buf, kt)                                                        \
  {                                                                              \
    _Pragma("unroll")                                                            \
    for (int is = 0; is < 4; ++is) {                                             \
      __builtin_amdgcn_global_load_lds(                                          \
          (AS1 uint32_t*)(srcA[is] + (kt) * 64),                                 \
          (AS3 uint32_t*)((AS3 char*)glds + (buf) * 16384 + dstoff[is]), 16, 0, 0); \
      __builtin_amdgcn_global_load_lds(                                          \
          (AS1 uint32_t*)(srcB[is] + (kt) * 64),                                 \
          (AS3 uint32_t*)((AS3 char*)glds + 32768 + (buf) * 16384 + dstoff[is]), \
          16, 0, 0);                                                             \
    }                                                                            \
  }

  uint32_t abase[4], ax[4], bbase[4], bx[4];
#pragma unroll
  for (int m = 0; m < 4; ++m) {
    const int arow = wr * 64 + m * 16 + r15;
    abase[m] = (uint32_t)(arow * 128);
    ax[m] = (uint32_t)(arow & 7);
  }
#pragma unroll
  for (int n = 0; n < 4; ++n) {
    const int brow = wc * 64 + n * 16 + r15;
    bbase[n] = (uint32_t)(brow * 128);
    bx[n] = (uint32_t)(brow & 7);
  }

  const int nk = K >> 6;
  GSTAGE64(0, 0);

  for (int kt = 0; kt < nk; ++kt) {
    const int cur = kt & 1;
    if (kt + 1 < nk) {
      GSTAGE64(cur ^ 1, kt + 1);
      asm volatile("s_waitcnt vmcnt(8)" ::: "memory");
    } else {
      asm volatile("s_waitcnt vmcnt(0)" ::: "memory");
    }
    __builtin_amdgcn_s_barrier();
    __builtin_amdgcn_sched_barrier(0);

    const char* Ac = (const char*)glds + cur * 16384;
    const char* Bc = (const char*)glds + 32768 + cur * 16384;

#pragma unroll
    for (int kk = 0; kk < 2; ++kk) {
      bf16x8 af[4], bfr[4];
#pragma unroll
      for (int m = 0; m < 4; ++m) {
        const uint32_t slot = (uint32_t)(kk * 4 + g) ^ ax[m];
        af[m] = *(const bf16x8*)(Ac + abase[m] + slot * 16);
      }
#pragma unroll
      for (int n = 0; n < 4; ++n) {
        const uint32_t slot = (uint32_t)(kk * 4 + g) ^ bx[n];
        bfr[n] = *(const bf16x8*)(Bc + bbase[n] + slot * 16);
      }
#pragma unroll
      for (int m = 0; m < 4; ++m)
#pragma unroll
        for (int n = 0; n < 4; ++n)
          acc[m][n] = __builtin_amdgcn_mfma_f32_16x16x32_bf16(af[m], bfr[n],
                                                              acc[m][n], 0, 0, 0);
    }
    __builtin_amdgcn_s_barrier();
  }
#undef GSTAGE64

#pragma unroll
  for (int n = 0; n < 4; ++n) {
    const int col = tileN + wc * 64 + n * 16 + r15;
    const float bv = bias[col];
#pragma unroll
    for (int m = 0; m < 4; ++m) {
      const int row0 = tileM + wr * 64 + m * 16 + g * 4;
#pragma unroll
      for (int j = 0; j < 4; ++j) {
        float v = acc[m][n][j] + bv;
        if (RELU) v = fmaxf(v, 0.f);
        C[(size_t)(row0 + j) * N + col] = (bf16)v;
      }
    }
  }
}

// ----------------------------------------------------------- flash attention
// Split-K over KV (r12), fixed-shift softmax m==0 (r13 body, VGPR 60 /
// occupancy 35.7% — r14's issue-early tr_reads crossed the 64-VGPR cliff and
// regressed; reverted). Only register-neutral r14 piece kept: the per-pass
// cross-half l-sum shfl is deferred to one shfl after the KV loop (exact).
__global__ __launch_bounds__(512) void attn_kernel(const bf16* __restrict__ qkv,
                                                   bf16* __restrict__ ctx) {
  __shared__ char lds[34816];   // 4 x 8KB dbuf (2 groups x 2 bufs) + 2KB m/l

  const int tid = threadIdx.x;
  const int lane = tid & 63;
  const int wv = tid >> 6;        // 0..7
  const int wq = wv & 3;          // q-subtile index
  const int grp = wv >> 2;        // KV half: 0 -> rows 0..511, 1 -> 512..1023
  const int l31 = lane & 31;
  const int h = lane >> 5;
  const int b = blockIdx.z, hd = blockIdx.y, qt = blockIdx.x;
  const size_t headoff = (size_t)b * SQ_ * DM_ + hd * DK_;
  const int q0 = qt * 128 + wq * 32;
  const int go = grp * 512;       // KV row offset for this group

  const float QS = 0.125f * L2E;
  bf16x8 aq[4];
#pragma unroll
  for (int kd = 0; kd < 4; ++kd) {
    const bf16* gq = qkv + headoff + (size_t)(q0 + l31) * DM_ + kd * 16 + h * 8;
    bf16x8 v = *(const bf16x8*)gq;
#pragma unroll
    for (int e = 0; e < 8; ++e) v[e] = (bf16)((float)v[e] * QS);
    aq[kd] = v;
  }

  f32x16 o0 = {}, o1 = {};
  float lstate = 0.f;

  const uint32_t ldsb = (uint32_t)(uintptr_t)(AS3 char*)lds;

  // ---- staging precompute (64-row subtiled tile, proven r9 formula)
  uint32_t dstoff[2];
  const bf16* srcb[2];
#pragma unroll
  for (int is = 0; is < 2; ++is) {
    const int ob = is * 4096 + wq * 1024 + lane * 16;
    const int e0 = ob >> 1;
    const int srow = ((e0 >> 8) << 2) + ((e0 >> 4) & 3);
    const int dcol = ((e0 >> 6) & 3) * 16 + ((e0 >> 3) & 1) * 8;
    dstoff[is] = (uint32_t)(grp * 16384 + is * 4096 + wq * 1024);
    srcb[is] = qkv + headoff + (size_t)(go + srow) * DM_ + dcol;
  }

#define STAGE(buf, t)                                                          \
  {                                                                            \
    _Pragma("unroll")                                                          \
    for (int is = 0; is < 2; ++is) {                                           \
      __builtin_amdgcn_global_load_lds(                                        \
          (AS1 uint32_t*)(srcb[is] + (size_t)(t) * 64 * DM_),                  \
          (AS3 uint32_t*)((AS3 char*)lds + (buf) * 8192 + dstoff[is]), 16, 0, 0); \
    }                                                                          \
  }

  constexpr int NT = 512 / 64;   // 8 passes per group
  STAGE(0, 0);

  for (int t = 0; t < NT; ++t) {
    const int cur = t & 1;
    // barrier #1: all waves done reading buf[cur^1] -> safe to overwrite
    __builtin_amdgcn_s_barrier();
    if (t + 1 < NT) {
      STAGE(cur ^ 1, t + 1);
      asm volatile("s_waitcnt vmcnt(2)" ::: "memory");   // my tile t's 2 loads
    } else {
      asm volatile("s_waitcnt vmcnt(0)" ::: "memory");
    }
    // barrier #2: all waves' stage of buf[cur] visible
    __builtin_amdgcn_s_barrier();
    __builtin_amdgcn_sched_barrier(0);

    const char* tile = (const char*)lds + grp * 16384 + cur * 8192;

    // ---- S^T = K · Q^T (log2 domain)
    f32x16 s0v = {}, s1v = {};
    const char* pabase = tile + (l31 >> 2) * 512 + (l31 & 3) * 32 + h * 16;
    __builtin_amdgcn_s_setprio(1);
#pragma unroll
    for (int kd = 0; kd < 4; ++kd) {
      bf16x8 a0 = *(const bf16x8*)(pabase + kd * 128);
      bf16x8 a1 = *(const bf16x8*)(pabase + kd * 128 + 4096);
      s0v = __builtin_amdgcn_mfma_f32_32x32x16_bf16(a0, aq[kd], s0v, 0, 0, 0);
      s1v = __builtin_amdgcn_mfma_f32_32x32x16_bf16(a1, aq[kd], s1v, 0, 0, 0);
    }
    __builtin_amdgcn_s_setprio(0);

    // ---- fixed-shift softmax accumulation: P = exp2(S), no max tracking
    // (cross-half sum deferred to after the KV loop)
    float rs = 0.f;
#pragma unroll
    for (int r = 0; r < 16; ++r) {
      float pq = exp2f(s0v[r]);
      s0v[r] = pq; rs += pq;
    }
#pragma unroll
    for (int r = 0; r < 16; ++r) {
      float pq = exp2f(s1v[r]);
      s1v[r] = pq; rs += pq;
    }
    lstate += rs;

    // ---- build PV B-fragments: bf16 pairs + permlane32_swap (proven)
    uint32_t pf[4][4];
#pragma unroll
    for (int ks = 0; ks < 4; ++ks) {
      const int kb = (ks & 1) * 8;
      float v0, v1, v2, v3, v4, v5, v6, v7;
      if (ks < 2) {
        v0 = s0v[kb+0]; v1 = s0v[kb+1]; v2 = s0v[kb+2]; v3 = s0v[kb+3];
        v4 = s0v[kb+4]; v5 = s0v[kb+5]; v6 = s0v[kb+6]; v7 = s0v[kb+7];
      } else {
        v0 = s1v[kb+0]; v1 = s1v[kb+1]; v2 = s1v[kb+2]; v3 = s1v[kb+3];
        v4 = s1v[kb+4]; v5 = s1v[kb+5]; v6 = s1v[kb+6]; v7 = s1v[kb+7];
      }
      union { bf16x2 v; uint32_t u; } P0, P1, P2, P3;
      P0.v = bf16x2{(bf16)v0, (bf16)v1};
      P1.v = bf16x2{(bf16)v2, (bf16)v3};
      P2.v = bf16x2{(bf16)v4, (bf16)v5};
      P3.v = bf16x2{(bf16)v6, (bf16)v7};
      asm volatile("v_permlane32_swap_b32 %0, %1" : "+v"(P0.u), "+v"(P2.u));
      asm volatile("v_permlane32_swap_b32 %0, %1" : "+v"(P1.u), "+v"(P3.u));
      pf[ks][0] = P0.u;
      pf[ks][1] = P1.u;
      pf[ks][2] = P2.u;
      pf[ks][3] = P3.u;
    }

    // ---- PV: Ot[d,q] += V^T-rows (tr-read) x P^T  (r13 placement, VGPR 60)
#pragma unroll
    for (int df = 0; df < 2; ++df) {
      const uint32_t vb = ldsb + grp * 16384 + cur * 8192 + df * 256 +
                          (lane & 15) * 8 + ((lane >> 4) & 1) * 128 +
                          (lane >> 5) * 1024;
      bf16x4 lo[4], hi[4];
#pragma unroll
      for (int ks = 0; ks < 4; ++ks) {
        asm volatile("ds_read_b64_tr_b16 %0, %2\n\t"
                     "ds_read_b64_tr_b16 %1, %2 offset:512"
                     : "=&v"(lo[ks]), "=&v"(hi[ks])
                     : "v"(vb + ks * 2048));
      }
      asm volatile("s_waitcnt lgkmcnt(0)" ::: "memory");
      __builtin_amdgcn_sched_barrier(0);
      __builtin_amdgcn_s_setprio(1);
#pragma unroll
      for (int ks = 0; ks < 4; ++ks) {
        union { struct { bf16x4 l, h; } pp; bf16x8 v; } av;
        av.pp.l = lo[ks]; av.pp.h = hi[ks];
        union { uint32_t u[4]; bf16x8 v; } bv;
        bv.u[0] = pf[ks][0]; bv.u[1] = pf[ks][1];
        bv.u[2] = pf[ks][2]; bv.u[3] = pf[ks][3];
        if (df == 0)
          o0 = __builtin_amdgcn_mfma_f32_32x32x16_bf16(av.v, bv.v, o0, 0, 0, 0);
        else
          o1 = __builtin_amdgcn_mfma_f32_32x32x16_bf16(av.v, bv.v, o1, 0, 0, 0);
      }
      __builtin_amdgcn_s_setprio(0);
    }
  }
#undef STAGE

  // ---- deferred cross-half l-sum (exact: plain sum with m==0)
  lstate += __shfl_xor(lstate, 32);

  // ---- flash combine (m==0 both groups: plain sums, no exp factors)
  __syncthreads();   // all staging reads done -> LDS reusable
  if (grp == 1) {
    float* dst = (float*)((char*)lds + wq * 8192) + lane * 32;
#pragma unroll
    for (int r = 0; r < 16; ++r) { dst[r] = o0[r]; dst[16 + r] = o1[r]; }
    float* ml = (float*)((char*)lds + 32768 + wq * 512 + lane * 8);
    *ml = lstate;
  }
  __syncthreads();
  if (grp == 0) {
    const float* src = (const float*)((char*)lds + wq * 8192) + lane * 32;
    const float lB = *(const float*)((const char*)lds + 32768 + wq * 512 + lane * 8);
    lstate += lB;
#pragma unroll
    for (int r = 0; r < 16; ++r) {
      o0[r] += src[r];
      o1[r] += src[16 + r];
    }
  }
  __syncthreads();   // merge reads done -> LDS reusable for transpose

  // ---- epilogue (group A only): normalize, per-wave transpose, store
  if (grp == 0) {
    const float invl = 1.f / lstate;
    char* wb = (char*)lds + wq * 4096;   // [q=32][d=64] bf16, XOR-swizzled
#pragma unroll
    for (int df = 0; df < 2; ++df)
#pragma unroll
      for (int t = 0; t < 4; ++t) {
        const f32x16& ov = df ? o1 : o0;
        bf16x4 pkt;
        pkt[0] = (bf16)(ov[4*t+0] * invl);
        pkt[1] = (bf16)(ov[4*t+1] * invl);
        pkt[2] = (bf16)(ov[4*t+2] * invl);
        pkt[3] = (bf16)(ov[4*t+3] * invl);
        const int byte = (l31 * 128 + df * 64 + t * 16 + h * 8) ^ ((l31 & 7) << 4);
        *(bf16x4*)(wb + byte) = pkt;
      }
#pragma unroll
    for (int ps = 0; ps < 4; ++ps) {
      const int qr = ps * 8 + (lane >> 3);
      const int byte = (qr * 128 + (lane & 7) * 16) ^ ((qr & 7) << 4);
      bf16x8 vv = *(const bf16x8*)(wb + byte);
      bf16* dst = ctx + (size_t)(b * SQ_ + q0 + qr) * DM_ + hd * 64 + (lane & 7) * 8;
      *(bf16x8*)dst = vv;
    }
  }
}

// ------------------------------------------------- dual LayerNorm residual #1
__global__ __launch_bounds__(256) void dual_ln_kernel(const bf16* __restrict__ x,
                                                      const bf16* __restrict__ attn,
                                                      const float* __restrict__ g1,
                                                      const float* __restrict__ be1,
                                                      bf16* __restrict__ out) {
  const int row = blockIdx.x * 4 + (threadIdx.x >> 6);
  const int lane = threadIdx.x & 63;
  bf16x8 xv = *(const bf16x8*)(x + (size_t)row * DM_ + lane * 8);
  bf16x8 av = *(const bf16x8*)(attn + (size_t)row * DM_ + lane * 8);
  float xs[8], as_[8];
#pragma unroll
  for (int e = 0; e < 8; ++e) { xs[e] = (float)xv[e]; as_[e] = (float)av[e]; }
  float sx = 0, sx2 = 0, sa = 0, sa2 = 0;
#pragma unroll
  for (int e = 0; e < 8; ++e) {
    sx += xs[e]; sx2 += xs[e] * xs[e];
    sa += as_[e]; sa2 += as_[e] * as_[e];
  }
#pragma unroll
  for (int off = 1; off < 64; off <<= 1) {
    sx += __shfl_xor(sx, off);  sx2 += __shfl_xor(sx2, off);
    sa += __shfl_xor(sa, off);  sa2 += __shfl_xor(sa2, off);
  }
  const float inv = 1.f / (float)DM_;
  const float mux = sx * inv, mua = sa * inv;
  const float rx = rsqrtf(fmaxf(sx2 * inv - mux * mux, 0.f) + 1e-5f);
  const float ra = rsqrtf(fmaxf(sa2 * inv - mua * mua, 0.f) + 1e-5f);
  bf16x8 ov;
#pragma unroll
  for (int e = 0; e < 8; ++e) {
    const int c = lane * 8 + e;
    const float val = ((xs[e] - mux) * rx + (as_[e] - mua) * ra) * g1[c] + 2.f * be1[c];
    ov[e] = (bf16)val;
  }
  *(bf16x8*)(out + (size_t)row * DM_ + lane * 8) = ov;
}

// ------------------------------------------------------ final LN residual #2
__global__ __launch_bounds__(256) void final_ln_kernel(const bf16* __restrict__ x1,
                                                       const bf16* __restrict__ ffn,
                                                       const float* __restrict__ g2,
                                                       const float* __restrict__ be2,
                                                       float* __restrict__ out) {
  const int row = blockIdx.x * 4 + (threadIdx.x >> 6);
  const int lane = threadIdx.x & 63;
  bf16x8 xv = *(const bf16x8*)(x1 + (size_t)row * DM_ + lane * 8);
  bf16x8 fv = *(const bf16x8*)(ffn + (size_t)row * DM_ + lane * 8);
  float fs[8];
#pragma unroll
  for (int e = 0; e < 8; ++e) fs[e] = (float)fv[e];
  float sf = 0, sf2 = 0;
#pragma unroll
  for (int e = 0; e < 8; ++e) { sf += fs[e]; sf2 += fs[e] * fs[e]; }
#pragma unroll
  for (int off = 1; off < 64; off <<= 1) {
    sf += __shfl_xor(sf, off);  sf2 += __shfl_xor(sf2, off);
  }
  const float inv = 1.f / (float)DM_;
  const float mu = sf * inv;
  const float rs = rsqrtf(fmaxf(sf2 * inv - mu * mu, 0.f) + 1e-5f);
  float ov[8];
#pragma unroll
  for (int e = 0; e < 8; ++e) {
    const int c = lane * 8 + e;
    ov[e] = (float)xv[e] + (fs[e] - mu) * rs * g2[c] + be2[c];
  }
  float* orow = out + (size_t)row * DM_ + lane * 8;
  float4 o0 = {ov[0], ov[1], ov[2], ov[3]};
  float4 o1 = {ov[4], ov[5], ov[6], ov[7]};
  ((float4*)orow)[0] = o0;
  ((float4*)orow)[1] = o1;
}

// ---------------------------------------------------------------------------
extern "C" void kernel_launch(void* const* d_in, const int* in_sizes, int n_in,
                              void* d_out, int out_size, void* d_ws, size_t ws_size,
                              hipStream_t stream) {
  const float* x     = (const float*)d_in[0];
  const float* w_qkv = (const float*)d_in[1];
  const float* b_qkv = (const float*)d_in[2];
  const float* w_out = (const float*)d_in[3];
  const float* b_out = (const float*)d_in[4];
  const float* w1    = (const float*)d_in[5];
  const float* b1    = (const float*)d_in[6];
  const float* w2    = (const float*)d_in[7];
  const float* b2    = (const float*)d_in[8];
  const float* g1    = (const float*)d_in[9];
  const float* be1   = (const float*)d_in[10];
  const float* g2    = (const float*)d_in[11];
  const float* be2   = (const float*)d_in[12];
  float* out = (float*)d_out;

  char* ws = (char*)d_ws;
  const size_t o_wqkv = 0;
  const size_t o_wout = o_wqkv + (size_t)DM_ * DM_ * 2;
  const size_t o_w1   = o_wout + (size_t)DM_ * DM_ * 2;
  const size_t o_w2   = o_w1 + (size_t)DFF_ * DM_ * 2;
  const size_t o_A    = o_w2 + (size_t)DM_ * DFF_ * 2;     // ctx_bf
  const size_t o_B    = o_A + (size_t)ROWS_ * DM_ * 2;     // qkv_bf -> x1_bf
  const size_t o_C    = o_B + (size_t)ROWS_ * DM_ * 2;     // attn_bf -> ffn_bf
  const size_t o_D    = o_C + (size_t)ROWS_ * DM_ * 2;     // x_bf -> h1_bf [ROWS,DFF]
  const size_t need   = o_D + (size_t)ROWS_ * DFF_ * 2;
  if (ws_size < need) return;

  bf16* wqkv_bf = (bf16*)(ws + o_wqkv);
  bf16* wout_bf = (bf16*)(ws + o_wout);
  bf16* w1_bf   = (bf16*)(ws + o_w1);
  bf16* w2_bf   = (bf16*)(ws + o_w2);
  bf16* bufA    = (bf16*)(ws + o_A);
  bf16* bufB    = (bf16*)(ws + o_B);
  bf16* bufC    = (bf16*)(ws + o_C);
  bf16* bufD    = (bf16*)(ws + o_D);   // x_bf lives here until ffn1 overwrites

  // 1. converts — single launch (x_bf parked in bufD; reused by GEMM1 + dual_ln)
  const int nx  = ROWS_ * DM_ / 8;       // 1048576
  const int nwq = DM_ * DM_ / 8;         // 32768
  const int nw1 = DFF_ * DM_ / 8;        // 131072
  const int ntot = nx + 2 * nwq + 2 * nw1;
  f2b5_kernel<<<dim3((ntot + 255) / 256), dim3(256), 0, stream>>>(
      x, bufD, nx,
      w_qkv, wqkv_bf, nwq,
      w_out, wout_bf, nwq,
      w1, w1_bf, nw1,
      w2, w2_bf, nw1);

  // 2. qkv = x @ w_qkv.T + b_qkv       [16384,512]  (BK=64)
  gemm_bt64<0><<<dim3(DM_ / 128, ROWS_ / 128), dim3(256), 0, stream>>>(bufD, wqkv_bf, b_qkv, bufB, ROWS_, DM_, DM_);

  // 3. self-attention (Q=K=V=qkv) -> ctx   (split-K, r13 body)
  attn_kernel<<<dim3(SQ_ / 128, NH_, BN_), dim3(512), 0, stream>>>(bufB, bufA);

  // 4. attn = ctx @ w_out.T + b_out    (BK=64)
  gemm_bt64<0><<<dim3(DM_ / 128, ROWS_ / 128), dim3(256), 0, stream>>>(bufA, wout_bf, b_out, bufC, ROWS_, DM_, DM_);

  // 5. x1 = LN(x) + LN(attn)   (x read as bf16 from bufD)
  dual_ln_kernel<<<dim3(ROWS_ / 4), dim3(256), 0, stream>>>(bufD, bufC, g1, be1, bufB);

  // 6. h1 = relu(x1 @ w1.T + b1)       [16384,2048]  (BK=32: keep 5 blocks/CU)
  gemm_bt<1><<<dim3(DFF_ / 128, ROWS_ / 128), dim3(256), 0, stream>>>(bufB, w1_bf, b1, bufD, ROWS_, DFF_, DM_);

  // 7. ffn = h1 @ w2.T + b2            [16384,512]  (BK=64)
  gemm_bt64<0><<<dim3(DM_ / 128, ROWS_ / 128), dim3(256), 0, stream>>>(bufD, w2_bf, b2, bufC, ROWS_, DM_, DFF_);

  // 8. out = x1 + LN(ffn)
  final_ln_kernel<<<dim3(ROWS_ / 4), dim3(256), 0, stream>>>(bufB, bufC, g2, be2, out);
}